// Round 1
// 737.633 us; speedup vs baseline: 1.0002x; 1.0002x over previous
//
#include <hip/hip_runtime.h>

typedef __bf16 bf16;
typedef __bf16 bf16x4 __attribute__((ext_vector_type(4)));
typedef __bf16 bf16x8 __attribute__((ext_vector_type(8)));
typedef float f32x4 __attribute__((ext_vector_type(4)));

#define LOG2E 1.4426950408889634f

// ---------------------------------------------------------------------------
// Projection: Out = X @ W^T + bias.  X:[4096,1024] f32, W:[1024,1024] f32.
// z=0 -> Q' (bf16, [4096,1024]), z=1 -> K' (same), z=2 -> V'^T per head:
//   vt[(b*1024 + n)*2048 + s]   (n = h*64+d), so attention can read V^T rows
//   with contiguous s (kk) for the MFMA B-operand layout.
// ---------------------------------------------------------------------------
__global__ __launch_bounds__(256, 2)
void proj_kernel(const float* __restrict__ Xq, const float* __restrict__ Xk,
                 const float* __restrict__ Xv,
                 const float* __restrict__ Wq, const float* __restrict__ Wk,
                 const float* __restrict__ Wv,
                 const float* __restrict__ Bq, const float* __restrict__ Bk,
                 const float* __restrict__ Bv,
                 bf16* __restrict__ Oq, bf16* __restrict__ Ok,
                 bf16* __restrict__ Ov)
{
    const int z = blockIdx.z;
    const float* X  = (z == 0) ? Xq : (z == 1) ? Xk : Xv;
    const float* W  = (z == 0) ? Wq : (z == 1) ? Wk : Wv;
    const float* Bi = (z == 0) ? Bq : (z == 1) ? Bk : Bv;

    const int n0 = blockIdx.x * 128;
    const int m0 = blockIdx.y * 128;

    __shared__ bf16 As[128 * 40];
    __shared__ bf16 Bs[128 * 40];

    const int t = threadIdx.x;
    const int w = t >> 6, l = t & 63, quad = l >> 4, ln = l & 15;
    const int wm = (w & 1) * 64, wn = (w >> 1) * 64;

    const f32x4 zero4 = {0.f, 0.f, 0.f, 0.f};
    f32x4 acc[4][4];
    for (int mi = 0; mi < 4; mi++)
        for (int ni = 0; ni < 4; ni++) acc[mi][ni] = zero4;

    for (int k0 = 0; k0 < 1024; k0 += 32) {
        for (int i = 0; i < 4; i++) {
            int idx = i * 256 + t;
            int row = idx >> 3, c4 = idx & 7;
            float4 a  = *(const float4*)&X[(size_t)(m0 + row) * 1024 + k0 + c4 * 4];
            float4 bb = *(const float4*)&W[(size_t)(n0 + row) * 1024 + k0 + c4 * 4];
            bf16x4 av, bv;
            av[0] = (bf16)a.x;  av[1] = (bf16)a.y;  av[2] = (bf16)a.z;  av[3] = (bf16)a.w;
            bv[0] = (bf16)bb.x; bv[1] = (bf16)bb.y; bv[2] = (bf16)bb.z; bv[3] = (bf16)bb.w;
            *(bf16x4*)&As[row * 40 + c4 * 4] = av;
            *(bf16x4*)&Bs[row * 40 + c4 * 4] = bv;
        }
        __syncthreads();

        bf16x8 af[4], bfv[4];
        for (int mi = 0; mi < 4; mi++)
            af[mi] = *(const bf16x8*)&As[(wm + mi * 16 + ln) * 40 + quad * 8];
        for (int ni = 0; ni < 4; ni++)
            bfv[ni] = *(const bf16x8*)&Bs[(wn + ni * 16 + ln) * 40 + quad * 8];
        for (int mi = 0; mi < 4; mi++)
            for (int ni = 0; ni < 4; ni++)
                acc[mi][ni] = __builtin_amdgcn_mfma_f32_16x16x32_bf16(
                    af[mi], bfv[ni], acc[mi][ni], 0, 0, 0);
        __syncthreads();
    }

    bf16* Onat = (z == 0) ? Oq : Ok;
    for (int ni = 0; ni < 4; ni++) {
        int n = n0 + wn + ni * 16 + ln;
        float bias = Bi[n];
        for (int mi = 0; mi < 4; mi++) {
            int mbase = m0 + wm + mi * 16 + quad * 4;
            if (z < 2) {
                for (int r = 0; r < 4; r++)
                    Onat[(size_t)(mbase + r) * 1024 + n] = (bf16)(acc[mi][ni][r] + bias);
            } else {
                int b = mbase >> 11, s0 = mbase & 2047;
                bf16x4 vv;
                for (int r = 0; r < 4; r++) vv[r] = (bf16)(acc[mi][ni][r] + bias);
                *(bf16x4*)&Ov[(size_t)(b * 1024 + n) * 2048 + s0] = vv;
            }
        }
    }
}

// ---------------------------------------------------------------------------
// Fused flash attention, TRANSPOSED score tile: ST = K·Q^T so each thread's
// 4 accumulator regs are 4 consecutive kk for a fixed q.
//   - scores streamed as nontemporal dwordx4 (4x fewer store instrs)
//   - P written to LDS as bf16x4 ds_write_b64 (4x fewer DS ops)
//   - softmax state: 2 scalars/thread, reductions = 2 shfl_xor (16,32)
//   - O accumulated transposed (d,q); epilogue also dwordx4
// Grid flattened (512) with XCD-chunked swizzle: all 16 q-tiles of a (b,h)
// land on one XCD -> K/V read once per L2.
// ---------------------------------------------------------------------------
__global__ __launch_bounds__(256, 2)
void attn_kernel(const bf16* __restrict__ Qp, const bf16* __restrict__ Kp,
                 const bf16* __restrict__ Vt, const float* __restrict__ mask,
                 float* __restrict__ ctx, float* __restrict__ scores)
{
    // XCD-chunked bijective swizzle: 512 blocks, 8 XCDs, 64 per XCD.
    const int lid = blockIdx.x;
    const int wg  = (lid & 7) * 64 + (lid >> 3);
    const int qt = wg & 15, h = (wg >> 4) & 15, b = wg >> 8;

    const int q0 = qt * 128;
    const int t = threadIdx.x, w = t >> 6, l = t & 63, quad = l >> 4, ln = l & 15;

    __shared__ bf16 Qs[128 * 72];   // [q][d]   ld=72
    __shared__ bf16 Ks[64 * 72];    // [kk][d]  ld=72
    __shared__ bf16 VTs[64 * 72];   // [d][kk]  ld=72
    __shared__ bf16 Ps[128 * 72];   // [q][kk]  ld=72 (per-wave private rows)

    // stage Q tile [128 x 64] once
    for (int i = 0; i < 4; i++) {
        int idx = i * 256 + t;
        int row = idx >> 3, d8 = idx & 7;
        *(bf16x8*)&Qs[row * 72 + d8 * 8] =
            *(const bf16x8*)&Qp[(size_t)(b * 2048 + q0 + row) * 1024 + h * 64 + d8 * 8];
    }
    __syncthreads();

    // Q fragments (B-operand now) in registers for the whole block
    bf16x8 qf[2][2];
#pragma unroll
    for (int mi = 0; mi < 2; mi++)
#pragma unroll
        for (int ks = 0; ks < 2; ks++)
            qf[mi][ks] = *(const bf16x8*)&Qs[(w * 32 + mi * 16 + ln) * 72 + ks * 32 + quad * 8];

    const f32x4 zero4 = {0.f, 0.f, 0.f, 0.f};
    f32x4 Ot[4][2];                 // [d-frag ni][q-frag mi], O^T layout
#pragma unroll
    for (int ni = 0; ni < 4; ni++)
#pragma unroll
        for (int mi = 0; mi < 2; mi++) Ot[ni][mi] = zero4;
    float mst[2] = {-1e30f, -1e30f};
    float lst[2] = {0.f, 0.f};

    for (int kt = 0; kt < 32; kt++) {
        const int kk0 = kt * 64;
        __syncthreads();   // previous iteration's LDS reads complete
        // stage K tile [64 kk x 64 d] and V^T tile [64 d x 64 kk]
        for (int i = 0; i < 2; i++) {
            int idx = i * 256 + t;
            int row = idx >> 3, d8 = idx & 7;
            *(bf16x8*)&Ks[row * 72 + d8 * 8] =
                *(const bf16x8*)&Kp[(size_t)(b * 2048 + kk0 + row) * 1024 + h * 64 + d8 * 8];
            *(bf16x8*)&VTs[row * 72 + d8 * 8] =
                *(const bf16x8*)&Vt[(size_t)(b * 1024 + h * 64 + row) * 2048 + kk0 + d8 * 8];
        }
        __syncthreads();

        // ST = K Q^T : row(m)=kk=quad*4+r (+16*ni), col(n)=q=ln (+16*mi)
        f32x4 st[4][2];
#pragma unroll
        for (int ni = 0; ni < 4; ni++)
#pragma unroll
            for (int mi = 0; mi < 2; mi++) st[ni][mi] = zero4;
#pragma unroll
        for (int ks = 0; ks < 2; ks++) {
            bf16x8 kf[4];
#pragma unroll
            for (int ni = 0; ni < 4; ni++)
                kf[ni] = *(const bf16x8*)&Ks[(ni * 16 + ln) * 72 + ks * 32 + quad * 8];
#pragma unroll
            for (int ni = 0; ni < 4; ni++)
#pragma unroll
                for (int mi = 0; mi < 2; mi++)
                    st[ni][mi] = __builtin_amdgcn_mfma_f32_16x16x32_bf16(
                        kf[ni], qf[mi][ks], st[ni][mi], 0, 0, 0);
        }

        // mask values: 4 consecutive kk per (ni) -> vector load
        f32x4 mv[4];
#pragma unroll
        for (int ni = 0; ni < 4; ni++)
            mv[ni] = *(const f32x4*)&mask[b * 2048 + kk0 + ni * 16 + quad * 4];

        // scale + mask + stream raw scores as nontemporal float4
#pragma unroll
        for (int mi = 0; mi < 2; mi++) {
            const size_t srow =
                ((size_t)((b * 16 + h) * 2048 + q0 + w * 32 + mi * 16 + ln)) * 2048 + kk0;
#pragma unroll
            for (int ni = 0; ni < 4; ni++) {
                f32x4 v = st[ni][mi];
#pragma unroll
                for (int r = 0; r < 4; r++) v[r] = v[r] * 0.125f + mv[ni][r];
                st[ni][mi] = v;
                __builtin_nontemporal_store(
                    v, (f32x4*)&scores[srow + ni * 16 + quad * 4]);
            }
        }

        // online softmax per q-row (state is 2 scalars/thread; q = ln + 16*mi)
#pragma unroll
        for (int mi = 0; mi < 2; mi++) {
            float rm = -1e30f;
#pragma unroll
            for (int ni = 0; ni < 4; ni++)
#pragma unroll
                for (int r = 0; r < 4; r++) rm = fmaxf(rm, st[ni][mi][r]);
            rm = fmaxf(rm, __shfl_xor(rm, 16));
            rm = fmaxf(rm, __shfl_xor(rm, 32));
            const float mnew  = fmaxf(mst[mi], rm);
            const float alpha = exp2f((mst[mi] - mnew) * LOG2E);
            mst[mi] = mnew;

            float rs = 0.f;
#pragma unroll
            for (int ni = 0; ni < 4; ni++) {
                bf16x4 pv;
#pragma unroll
                for (int r = 0; r < 4; r++) {
                    float p = exp2f((st[ni][mi][r] - mnew) * LOG2E);
                    rs += p;
                    pv[r] = (bf16)p;
                }
                // P[q][kk]: 4 contiguous kk -> single ds_write_b64
                *(bf16x4*)&Ps[(w * 32 + mi * 16 + ln) * 72 + ni * 16 + quad * 4] = pv;
            }
            rs += __shfl_xor(rs, 16);
            rs += __shfl_xor(rs, 32);
            lst[mi] = lst[mi] * alpha + rs;

            // rescale O^T columns of this q-frag (alpha uniform per vector)
#pragma unroll
            for (int ni = 0; ni < 4; ni++)
#pragma unroll
                for (int r = 0; r < 4; r++) Ot[ni][mi][r] *= alpha;
        }

        // O^T += V^T P^T  (A: m=ln -> d from VTs; B: n=ln -> q from Ps)
#pragma unroll
        for (int ks = 0; ks < 2; ks++) {
            bf16x8 vf[4], pf[2];
#pragma unroll
            for (int ni = 0; ni < 4; ni++)
                vf[ni] = *(const bf16x8*)&VTs[(ni * 16 + ln) * 72 + ks * 32 + quad * 8];
#pragma unroll
            for (int mi = 0; mi < 2; mi++)
                pf[mi] = *(const bf16x8*)&Ps[(w * 32 + mi * 16 + ln) * 72 + ks * 32 + quad * 8];
#pragma unroll
            for (int ni = 0; ni < 4; ni++)
#pragma unroll
                for (int mi = 0; mi < 2; mi++)
                    Ot[ni][mi] = __builtin_amdgcn_mfma_f32_16x16x32_bf16(
                        vf[ni], pf[mi], Ot[ni][mi], 0, 0, 0);
        }
    }

    // epilogue: ctx[q][d] = O^T[d][q] / l  -> 4 consecutive d per thread = float4
#pragma unroll
    for (int mi = 0; mi < 2; mi++) {
        const float rl = 1.0f / lst[mi];
        const int row = b * 2048 + q0 + w * 32 + mi * 16 + ln;
#pragma unroll
        for (int ni = 0; ni < 4; ni++) {
            f32x4 o = Ot[ni][mi];
#pragma unroll
            for (int r = 0; r < 4; r++) o[r] *= rl;
            *(f32x4*)&ctx[(size_t)row * 1024 + h * 64 + ni * 16 + quad * 4] = o;
        }
    }
}

extern "C" void kernel_launch(void* const* d_in, const int* in_sizes, int n_in,
                              void* d_out, int out_size, void* d_ws, size_t ws_size,
                              hipStream_t stream) {
    const float* q    = (const float*)d_in[0];
    const float* k    = (const float*)d_in[1];
    const float* v    = (const float*)d_in[2];
    const float* mask = (const float*)d_in[3];
    const float* Wq   = (const float*)d_in[4];
    const float* bq   = (const float*)d_in[5];
    const float* Wk   = (const float*)d_in[6];
    const float* bk   = (const float*)d_in[7];
    const float* Wv   = (const float*)d_in[8];
    const float* bv   = (const float*)d_in[9];

    bf16* Qp = (bf16*)d_ws;                 // [4096,1024]
    bf16* Kp = Qp + (size_t)4096 * 1024;    // [4096,1024]
    bf16* Vt = Kp + (size_t)4096 * 1024;    // [B*1024, 2048] = V'^T per head

    float* ctx    = (float*)d_out;                    // [2,2048,1024]
    float* scores = ctx + (size_t)2 * 2048 * 1024;    // [2,16,2048,2048]

    proj_kernel<<<dim3(8, 32, 3), 256, 0, stream>>>(
        q, k, v, Wq, Wk, Wv, bq, bk, bv, Qp, Kp, Vt);
    attn_kernel<<<dim3(512, 1, 1), 256, 0, stream>>>(
        Qp, Kp, Vt, mask, ctx, scores);
}